// Round 1
// baseline (728.012 us; speedup 1.0000x reference)
//
#include <hip/hip_runtime.h>
#include <hip/hip_bf16.h>

#define H 8
#define C 16
#define HC 128          // H*C
#define NEG 0.2f
#define SCAN_B 256
#define XS_S 132        // LDS row stride (floats) for k1 x-tile

__device__ __forceinline__ float lrelu(float x) { return x > 0.f ? x : NEG * x; }

__device__ __forceinline__ unsigned pack_bf16(float a, float b) {
    union { __hip_bfloat16 h; unsigned short u; } ua, ub;
    ua.h = __float2bfloat16(a);
    ub.h = __float2bfloat16(b);
    return (unsigned)ua.u | ((unsigned)ub.u << 16);
}
__device__ __forceinline__ float bf_lo(unsigned d) { return __uint_as_float(d << 16); }
__device__ __forceinline__ float bf_hi(unsigned d) { return __uint_as_float(d & 0xffff0000u); }

// K1: h = x @ W, fp32 register-tiled GEMM, bf16-packed output.
// Block 256 threads -> 64(rows) x 128(cols) tile. x tile in LDS (33 KB,
// 4 blocks/CU); W streamed through L1 (same 512 B row hit by all waves).
__global__ void __launch_bounds__(256) k1_gemm(const float* __restrict__ x,
                                               const float* __restrict__ W,
                                               unsigned* __restrict__ h16, int N) {
    __shared__ float xs[64 * XS_S];
    const int n0 = blockIdx.x * 64;
    const int t = threadIdx.x;
#pragma unroll
    for (int i = 0; i < 8; ++i) {
        int id = t + 256 * i;           // 2048 float4-chunks
        int r = id >> 5, kq = id & 31;
        int n = n0 + r;
        float4 v = (n < N) ? ((const float4*)x)[(size_t)n * 32 + kq]
                           : make_float4(0.f, 0.f, 0.f, 0.f);
        *(float4*)&xs[r * XS_S + kq * 4] = v;
    }
    __syncthreads();
    const int cg = t & 31;        // cols cg*4..+3
    const int r0 = (t >> 5) * 8;  // rows r0..r0+7
    float acc[8][4];
#pragma unroll
    for (int i = 0; i < 8; ++i)
#pragma unroll
        for (int j = 0; j < 4; ++j) acc[i][j] = 0.f;

#pragma unroll 4
    for (int k = 0; k < HC; ++k) {
        const float4 wv = ((const float4*)W)[k * 32 + cg];
        float wr[4] = {wv.x, wv.y, wv.z, wv.w};
#pragma unroll
        for (int i = 0; i < 8; ++i) {
            float xv = xs[(r0 + i) * XS_S + k];   // broadcast across cg lanes
#pragma unroll
            for (int j = 0; j < 4; ++j) acc[i][j] += xv * wr[j];
        }
    }
#pragma unroll
    for (int i = 0; i < 8; ++i) {
        int n = n0 + r0 + i;
        if (n < N) {
            uint2 dv = make_uint2(pack_bf16(acc[i][0], acc[i][1]),
                                  pack_bf16(acc[i][2], acc[i][3]));
            *(uint2*)&h16[(size_t)n * 64 + cg * 2] = dv;
        }
    }
}

// K_ATT: per-(node,head) attention logits from bf16 h.
__global__ void k_att(const unsigned* __restrict__ h16,
                      const float* __restrict__ att_src,
                      const float* __restrict__ att_dst,
                      float* __restrict__ a_src,
                      float* __restrict__ a_dst, int NH) {
    int idx = blockIdx.x * blockDim.x + threadIdx.x;
    if (idx >= NH) return;
    int n = idx >> 3, hd = idx & 7;
    float s = 0.f, d = 0.f;
#pragma unroll
    for (int c2 = 0; c2 < 8; ++c2) {
        unsigned dv = h16[(size_t)n * 64 + hd * 8 + c2];
        float h0 = bf_lo(dv), h1 = bf_hi(dv);
        s += h0 * att_src[hd * C + 2 * c2] + h1 * att_src[hd * C + 2 * c2 + 1];
        d += h0 * att_dst[hd * C + 2 * c2] + h1 * att_dst[hd * C + 2 * c2 + 1];
    }
    a_src[idx] = s;
    a_dst[idx] = d;
}

// ---- CSR build (by destination) ----

__global__ void kc_count(const int* __restrict__ ei, int* __restrict__ deg, int E) {
    int i = blockIdx.x * blockDim.x + threadIdx.x;
    int E4 = E >> 2;
    if (i < E4) {
        int4 d4 = ((const int4*)(ei + E))[i];
        atomicAdd(&deg[d4.x], 1);
        atomicAdd(&deg[d4.y], 1);
        atomicAdd(&deg[d4.z], 1);
        atomicAdd(&deg[d4.w], 1);
    }
    if (i < (E & 3)) atomicAdd(&deg[ei[E + (E4 << 2) + i]], 1);
}

__global__ void ks_chunk(const int* __restrict__ deg, int* __restrict__ incl,
                         int* __restrict__ bsum, int N) {
    __shared__ int s[SCAN_B];
    int g = blockIdx.x * SCAN_B + threadIdx.x;
    s[threadIdx.x] = (g < N) ? deg[g] : 0;
    __syncthreads();
    for (int off = 1; off < SCAN_B; off <<= 1) {
        int v = (threadIdx.x >= off) ? s[threadIdx.x - off] : 0;
        __syncthreads();
        s[threadIdx.x] += v;
        __syncthreads();
    }
    if (g < N) incl[g] = s[threadIdx.x];
    if (threadIdx.x == SCAN_B - 1) bsum[blockIdx.x] = s[SCAN_B - 1];
}

__global__ void ks_bsum(int* __restrict__ bsum, int nb) {
    __shared__ int s[512];
    int t = threadIdx.x;
    s[t] = (t < nb) ? bsum[t] : 0;
    __syncthreads();
    for (int off = 1; off < 512; off <<= 1) {
        int v = (t >= off) ? s[t - off] : 0;
        __syncthreads();
        s[t] += v;
        __syncthreads();
    }
    if (t < nb) bsum[t] = s[t];
}

__global__ void ks_rowptr(const int* __restrict__ incl, const int* __restrict__ bsum,
                          const int* __restrict__ deg,
                          int* __restrict__ rowptr, int* __restrict__ cursor, int N) {
    int g = blockIdx.x * SCAN_B + threadIdx.x;
    if (g == 0) rowptr[0] = 0;
    if (g < N) {
        int off = (blockIdx.x == 0) ? 0 : bsum[blockIdx.x - 1];
        int inc = incl[g] + off;
        rowptr[g + 1] = inc;
        cursor[g] = inc - deg[g];
    }
}

// KC_SCATTER: place src in its CSR slot. Payload is now only 4 B/edge —
// the softmax numerator w is recomputed on the fly in k_pull (a_src is a
// 3.2 MB L2-resident array), eliminating the 51 MB w16 scatter and its
// ~4x write-amplification / RMW-fetch traffic.
__global__ void kc_scatter(const int* __restrict__ ei,
                           int* __restrict__ cursor, int* __restrict__ col, int E) {
    int e = blockIdx.x * blockDim.x + threadIdx.x;
    if (e >= E) return;
    int dst = ei[E + e], src = ei[e];
    int pos = atomicAdd(&cursor[dst], 1);
    col[pos] = src;
}

// K_PULL: one wave per node, lane t owns channels {2t,2t+1}, head t>>3.
// w = exp(lrelu(a_src[src]+a_dst[node])) computed in-register per edge:
// a_dst term is a per-lane constant, a_src gather is a 32 B broadcast per
// edge from an L2-resident array. No max subtraction needed: alpha in
// ~[-6, 8] -> exp in [2e-3, 3e3], fp32-safe.
__global__ void __launch_bounds__(256) k_pull(const int* __restrict__ rowptr,
                                              const int* __restrict__ col,
                                              const unsigned* __restrict__ h16,
                                              const float* __restrict__ a_src,
                                              const float* __restrict__ a_dst,
                                              const float* __restrict__ bias,
                                              float* __restrict__ out, int N) {
    const int node = blockIdx.x * 4 + (threadIdx.x >> 6);
    if (node >= N) return;
    const int t = threadIdx.x & 63;
    const int hd = t >> 3;
    const float adst = a_dst[node * H + hd];
    const float wself = __expf(lrelu(a_src[node * H + hd] + adst));
    unsigned dself = h16[(size_t)node * 64 + t];
    float a0 = bf_lo(dself) * wself, a1 = bf_hi(dself) * wself;
    float b0 = 0.f, b1 = 0.f, c0 = 0.f, c1 = 0.f, e0 = 0.f, e1 = 0.f;
    float sA = wself, sB = 0.f, sC = 0.f, sD = 0.f;

    const int beg = rowptr[node], end = rowptr[node + 1];
    int j = beg;
    for (; j + 4 <= end; j += 4) {
        int nA = col[j], nB = col[j + 1], nC = col[j + 2], nD = col[j + 3];
        float wA = __expf(lrelu(a_src[(size_t)nA * H + hd] + adst));
        float wB = __expf(lrelu(a_src[(size_t)nB * H + hd] + adst));
        float wC = __expf(lrelu(a_src[(size_t)nC * H + hd] + adst));
        float wD = __expf(lrelu(a_src[(size_t)nD * H + hd] + adst));
        unsigned dA = h16[(size_t)nA * 64 + t];
        unsigned dB = h16[(size_t)nB * 64 + t];
        unsigned dC = h16[(size_t)nC * 64 + t];
        unsigned dD = h16[(size_t)nD * 64 + t];
        a0 += bf_lo(dA) * wA; a1 += bf_hi(dA) * wA; sA += wA;
        b0 += bf_lo(dB) * wB; b1 += bf_hi(dB) * wB; sB += wB;
        c0 += bf_lo(dC) * wC; c1 += bf_hi(dC) * wC; sC += wC;
        e0 += bf_lo(dD) * wD; e1 += bf_hi(dD) * wD; sD += wD;
    }
    for (; j < end; ++j) {
        int nA = col[j];
        float wA = __expf(lrelu(a_src[(size_t)nA * H + hd] + adst));
        unsigned dA = h16[(size_t)nA * 64 + t];
        a0 += bf_lo(dA) * wA; a1 += bf_hi(dA) * wA; sA += wA;
    }
    const float s = sA + sB + sC + sD;
    const float inv = 1.f / (s + 1e-16f);
    const float acc0 = a0 + b0 + c0 + e0;
    const float acc1 = a1 + b1 + c1 + e1;
    const float2 bv = ((const float2*)bias)[t];
    float2 o;
    o.x = acc0 * inv + bv.x;
    o.y = acc1 * inv + bv.y;
    ((float2*)out)[(size_t)node * 64 + t] = o;
}

extern "C" void kernel_launch(void* const* d_in, const int* in_sizes, int n_in,
                              void* d_out, int out_size, void* d_ws, size_t ws_size,
                              hipStream_t stream) {
    const float* x       = (const float*)d_in[0];
    const int*   ei      = (const int*)d_in[1];
    const float* W       = (const float*)d_in[2];
    const float* att_src = (const float*)d_in[3];
    const float* att_dst = (const float*)d_in[4];
    const float* bias    = (const float*)d_in[5];
    float* out = (float*)d_out;

    const int N = in_sizes[0] / HC;
    const int E = in_sizes[1] / 2;
    const int nb = (N + SCAN_B - 1) / SCAN_B;   // <=512 required for ks_bsum

    // ws: h16[N*64]u32 | a_src[N*8]f | a_dst[N*8]f | deg[N] | incl[N] |
    //     bsum[nb] | rowptr[N+1] | cursor[N] | col[E]  (~47 MB)
    unsigned* h16 = (unsigned*)d_ws;
    float* a_src  = (float*)(h16 + (size_t)N * 64);
    float* a_dst  = a_src + (size_t)N * H;
    int* deg      = (int*)(a_dst + (size_t)N * H);
    int* incl     = deg + N;
    int* bsum     = incl + N;
    int* rowptr   = bsum + nb;
    int* cursor   = rowptr + (N + 1);
    int* col      = cursor + N;

    (void)hipMemsetAsync(deg, 0, (size_t)N * sizeof(int), stream);

    k1_gemm<<<(N + 63) / 64, 256, 0, stream>>>(x, W, h16, N);

    kc_count<<<(E / 4 + 255) / 256, 256, 0, stream>>>(ei, deg, E);
    ks_chunk<<<nb, SCAN_B, 0, stream>>>(deg, incl, bsum, N);
    ks_bsum<<<1, 512, 0, stream>>>(bsum, nb);
    ks_rowptr<<<nb, SCAN_B, 0, stream>>>(incl, bsum, deg, rowptr, cursor, N);

    kc_scatter<<<(E + 255) / 256, 256, 0, stream>>>(ei, cursor, col, E);

    k_att<<<(N * H + 255) / 256, 256, 0, stream>>>(h16, att_src, att_dst,
                                                   a_src, a_dst, N * H);

    k_pull<<<(N + 3) / 4, 256, 0, stream>>>(rowptr, col, h16, a_src,
                                            a_dst, bias, out, N);
}

// Round 2
// 451.507 us; speedup vs baseline: 1.6124x; 1.6124x over previous
//
#include <hip/hip_runtime.h>
#include <hip/hip_bf16.h>

#define H 8
#define C 16
#define HC 128          // H*C
#define NEG 0.2f
#define XS_S 132        // LDS row stride (floats) for k1 x-tile

#define BKT_SH 8        // 256 nodes per bucket
#define BKT_MSK 255
#define MAXB 1024       // supports N <= 262144 (src also packs into 18 bits)
#define EPB 4096        // edges per bin/hist block

__device__ __forceinline__ float lrelu(float x) { return x > 0.f ? x : NEG * x; }

__device__ __forceinline__ unsigned pack_bf16(float a, float b) {
    union { __hip_bfloat16 h; unsigned short u; } ua, ub;
    ua.h = __float2bfloat16(a);
    ub.h = __float2bfloat16(b);
    return (unsigned)ua.u | ((unsigned)ub.u << 16);
}
__device__ __forceinline__ float bf_lo(unsigned d) { return __uint_as_float(d << 16); }
__device__ __forceinline__ float bf_hi(unsigned d) { return __uint_as_float(d & 0xffff0000u); }

// K1: h = x @ W, fp32 register-tiled GEMM, bf16-packed output.
__global__ void __launch_bounds__(256) k1_gemm(const float* __restrict__ x,
                                               const float* __restrict__ W,
                                               unsigned* __restrict__ h16, int N) {
    __shared__ float xs[64 * XS_S];
    const int n0 = blockIdx.x * 64;
    const int t = threadIdx.x;
#pragma unroll
    for (int i = 0; i < 8; ++i) {
        int id = t + 256 * i;           // 2048 float4-chunks
        int r = id >> 5, kq = id & 31;
        int n = n0 + r;
        float4 v = (n < N) ? ((const float4*)x)[(size_t)n * 32 + kq]
                           : make_float4(0.f, 0.f, 0.f, 0.f);
        *(float4*)&xs[r * XS_S + kq * 4] = v;
    }
    __syncthreads();
    const int cg = t & 31;        // cols cg*4..+3
    const int r0 = (t >> 5) * 8;  // rows r0..r0+7
    float acc[8][4];
#pragma unroll
    for (int i = 0; i < 8; ++i)
#pragma unroll
        for (int j = 0; j < 4; ++j) acc[i][j] = 0.f;

#pragma unroll 4
    for (int k = 0; k < HC; ++k) {
        const float4 wv = ((const float4*)W)[k * 32 + cg];
        float wr[4] = {wv.x, wv.y, wv.z, wv.w};
#pragma unroll
        for (int i = 0; i < 8; ++i) {
            float xv = xs[(r0 + i) * XS_S + k];   // broadcast across cg lanes
#pragma unroll
            for (int j = 0; j < 4; ++j) acc[i][j] += xv * wr[j];
        }
    }
#pragma unroll
    for (int i = 0; i < 8; ++i) {
        int n = n0 + r0 + i;
        if (n < N) {
            uint2 dv = make_uint2(pack_bf16(acc[i][0], acc[i][1]),
                                  pack_bf16(acc[i][2], acc[i][3]));
            *(uint2*)&h16[(size_t)n * 64 + cg * 2] = dv;
        }
    }
}

// K_ATT: per-(node,head) attention logits from bf16 h.
__global__ void k_att(const unsigned* __restrict__ h16,
                      const float* __restrict__ att_src,
                      const float* __restrict__ att_dst,
                      float* __restrict__ a_src,
                      float* __restrict__ a_dst, int NH) {
    int idx = blockIdx.x * blockDim.x + threadIdx.x;
    if (idx >= NH) return;
    int n = idx >> 3, hd = idx & 7;
    float s = 0.f, d = 0.f;
#pragma unroll
    for (int c2 = 0; c2 < 8; ++c2) {
        unsigned dv = h16[(size_t)n * 64 + hd * 8 + c2];
        float h0 = bf_lo(dv), h1 = bf_hi(dv);
        s += h0 * att_src[hd * C + 2 * c2] + h1 * att_src[hd * C + 2 * c2 + 1];
        d += h0 * att_dst[hd * C + 2 * c2] + h1 * att_dst[hd * C + 2 * c2 + 1];
    }
    a_src[idx] = s;
    a_dst[idx] = d;
}

// ---- CSR build via bucketed counting sort (no far atomics) ----

// KH_BUCKET: per-block LDS histogram of dst>>BKT_SH, merged into bcount.
__global__ void __launch_bounds__(256) kh_bucket(const int* __restrict__ ei,
                                                 int* __restrict__ bcount,
                                                 int E, int B) {
    __shared__ int hist[MAXB];
    const int t = threadIdx.x;
    for (int i = t; i < B; i += 256) hist[i] = 0;
    __syncthreads();
    const int e0 = blockIdx.x * EPB;
    const int nE = min(EPB, E - e0);
    for (int i = t; i < nE; i += 256)
        atomicAdd(&hist[ei[E + e0 + i] >> BKT_SH], 1);
    __syncthreads();
    for (int i = t; i < B; i += 256)
        if (hist[i]) atomicAdd(&bcount[i], hist[i]);
}

// KSCAN_B: single-block scan of bucket counts -> bptr[0..B], init gcursor,
// and rowptr[N] = E.
__global__ void __launch_bounds__(1024) kscan_b(const int* __restrict__ bcount,
                                                int* __restrict__ bptr,
                                                int* __restrict__ gcursor,
                                                int* __restrict__ rowptr,
                                                int N, int B, int E) {
    __shared__ int s[MAXB];
    const int t = threadIdx.x;
    s[t] = (t < B) ? bcount[t] : 0;
    __syncthreads();
    for (int off = 1; off < MAXB; off <<= 1) {
        int v = (t >= off) ? s[t - off] : 0;
        __syncthreads();
        s[t] += v;
        __syncthreads();
    }
    if (t < B) {
        bptr[t + 1] = s[t];
        gcursor[t] = s[t] - bcount[t];   // exclusive base
    }
    if (t == 0) { bptr[0] = 0; rowptr[N] = E; }
}

// KB_BIN: partition edges into bucket-contiguous pairs[]. Each block builds an
// LDS histogram of its EPB-edge chunk, reserves per-bucket ranges with ONE
// global atomic per (block,bucket), then deposits packed (src | ldst<<18)
// via LDS cursors. Writes land in ~40-170 B runs per bucket -> line-friendly.
__global__ void __launch_bounds__(256) kb_bin(const int* __restrict__ ei,
                                              int* __restrict__ gcursor,
                                              unsigned* __restrict__ pairs,
                                              int E, int B) {
    __shared__ int hist[MAXB];
    __shared__ int lbase[MAXB];
    const int t = threadIdx.x;
    const int e0 = blockIdx.x * EPB;
    const int nE = min(EPB, E - e0);
    for (int i = t; i < B; i += 256) hist[i] = 0;
    __syncthreads();
    for (int i = t; i < nE; i += 256)
        atomicAdd(&hist[ei[E + e0 + i] >> BKT_SH], 1);
    __syncthreads();
    for (int i = t; i < B; i += 256) {
        int h = hist[i];
        if (h) lbase[i] = atomicAdd(&gcursor[i], h);
    }
    __syncthreads();
    for (int i = t; i < nE; i += 256) {
        int dst = ei[E + e0 + i];
        int src = ei[e0 + i];
        int b = dst >> BKT_SH;
        int pos = atomicAdd(&lbase[b], 1);
        pairs[pos] = (unsigned)src | ((unsigned)(dst & BKT_MSK) << 18);
    }
}

// KB_FINAL: one block per bucket. Count per-node degrees in LDS, scan in LDS
// (bucket-contiguity means rowptr[n] = bptr[b] + local_excl), write rowptr
// coalesced, then scatter col within the bucket's 32 KB L2-resident window
// using LDS cursors. No global atomics at all.
__global__ void __launch_bounds__(256) kb_final(const unsigned* __restrict__ pairs,
                                                const int* __restrict__ bptr,
                                                int* __restrict__ rowptr,
                                                int* __restrict__ col, int N) {
    __shared__ int cnt[256];
    __shared__ int incl[256];
    __shared__ int lcur[256];
    const int b = blockIdx.x;
    const int t = threadIdx.x;
    const int n0 = b << BKT_SH;
    const int jbeg = bptr[b], jend = bptr[b + 1];
    cnt[t] = 0;
    __syncthreads();
    for (int j = jbeg + t; j < jend; j += 256)
        atomicAdd(&cnt[pairs[j] >> 18], 1);
    __syncthreads();
    incl[t] = cnt[t];
    __syncthreads();
    for (int off = 1; off < 256; off <<= 1) {
        int v = (t >= off) ? incl[t - off] : 0;
        __syncthreads();
        incl[t] += v;
        __syncthreads();
    }
    const int base = jbeg + incl[t] - cnt[t];
    if (n0 + t < N) rowptr[n0 + t] = base;
    lcur[t] = base;
    __syncthreads();
    for (int j = jbeg + t; j < jend; j += 256) {
        unsigned v = pairs[j];
        int pos = atomicAdd(&lcur[v >> 18], 1);
        col[pos] = (int)(v & 0x3FFFF);
    }
}

// K_PULL: one wave per node, lane t owns channels {2t,2t+1}, head t>>3.
// w = exp(lrelu(a_src[src]+a_dst[node])) recomputed in-register per edge.
__global__ void __launch_bounds__(256) k_pull(const int* __restrict__ rowptr,
                                              const int* __restrict__ col,
                                              const unsigned* __restrict__ h16,
                                              const float* __restrict__ a_src,
                                              const float* __restrict__ a_dst,
                                              const float* __restrict__ bias,
                                              float* __restrict__ out, int N) {
    const int node = blockIdx.x * 4 + (threadIdx.x >> 6);
    if (node >= N) return;
    const int t = threadIdx.x & 63;
    const int hd = t >> 3;
    const float adst = a_dst[node * H + hd];
    const float wself = __expf(lrelu(a_src[node * H + hd] + adst));
    unsigned dself = h16[(size_t)node * 64 + t];
    float a0 = bf_lo(dself) * wself, a1 = bf_hi(dself) * wself;
    float b0 = 0.f, b1 = 0.f, c0 = 0.f, c1 = 0.f, e0 = 0.f, e1 = 0.f;
    float sA = wself, sB = 0.f, sC = 0.f, sD = 0.f;

    const int beg = rowptr[node], end = rowptr[node + 1];
    int j = beg;
    for (; j + 4 <= end; j += 4) {
        int nA = col[j], nB = col[j + 1], nC = col[j + 2], nD = col[j + 3];
        float wA = __expf(lrelu(a_src[(size_t)nA * H + hd] + adst));
        float wB = __expf(lrelu(a_src[(size_t)nB * H + hd] + adst));
        float wC = __expf(lrelu(a_src[(size_t)nC * H + hd] + adst));
        float wD = __expf(lrelu(a_src[(size_t)nD * H + hd] + adst));
        unsigned dA = h16[(size_t)nA * 64 + t];
        unsigned dB = h16[(size_t)nB * 64 + t];
        unsigned dC = h16[(size_t)nC * 64 + t];
        unsigned dD = h16[(size_t)nD * 64 + t];
        a0 += bf_lo(dA) * wA; a1 += bf_hi(dA) * wA; sA += wA;
        b0 += bf_lo(dB) * wB; b1 += bf_hi(dB) * wB; sB += wB;
        c0 += bf_lo(dC) * wC; c1 += bf_hi(dC) * wC; sC += wC;
        e0 += bf_lo(dD) * wD; e1 += bf_hi(dD) * wD; sD += wD;
    }
    for (; j < end; ++j) {
        int nA = col[j];
        float wA = __expf(lrelu(a_src[(size_t)nA * H + hd] + adst));
        unsigned dA = h16[(size_t)nA * 64 + t];
        a0 += bf_lo(dA) * wA; a1 += bf_hi(dA) * wA; sA += wA;
    }
    const float s = sA + sB + sC + sD;
    const float inv = 1.f / (s + 1e-16f);
    const float acc0 = a0 + b0 + c0 + e0;
    const float acc1 = a1 + b1 + c1 + e1;
    const float2 bv = ((const float2*)bias)[t];
    float2 o;
    o.x = acc0 * inv + bv.x;
    o.y = acc1 * inv + bv.y;
    ((float2*)out)[(size_t)node * 64 + t] = o;
}

extern "C" void kernel_launch(void* const* d_in, const int* in_sizes, int n_in,
                              void* d_out, int out_size, void* d_ws, size_t ws_size,
                              hipStream_t stream) {
    const float* x       = (const float*)d_in[0];
    const int*   ei      = (const int*)d_in[1];
    const float* W       = (const float*)d_in[2];
    const float* att_src = (const float*)d_in[3];
    const float* att_dst = (const float*)d_in[4];
    const float* bias    = (const float*)d_in[5];
    float* out = (float*)d_out;

    const int N = in_sizes[0] / HC;
    const int E = in_sizes[1] / 2;
    const int B = (N + BKT_MSK) >> BKT_SH;     // buckets of 256 nodes (<= MAXB)
    const int nbin = (E + EPB - 1) / EPB;

    // ws: h16[N*64]u32 | a_src[N*8]f | a_dst[N*8]f | bcount[MAXB] |
    //     bptr[MAXB+1] | gcursor[MAXB] | rowptr[N+1] | col[E] | pairs[E]
    unsigned* h16 = (unsigned*)d_ws;
    float* a_src  = (float*)(h16 + (size_t)N * 64);
    float* a_dst  = a_src + (size_t)N * H;
    int* bcount   = (int*)(a_dst + (size_t)N * H);
    int* bptr     = bcount + MAXB;
    int* gcursor  = bptr + (MAXB + 1);
    int* rowptr   = gcursor + MAXB;
    int* col      = rowptr + (N + 1);
    unsigned* pairs = (unsigned*)(col + E);

    (void)hipMemsetAsync(bcount, 0, MAXB * sizeof(int), stream);

    k1_gemm<<<(N + 63) / 64, 256, 0, stream>>>(x, W, h16, N);

    kh_bucket<<<nbin, 256, 0, stream>>>(ei, bcount, E, B);
    kscan_b<<<1, 1024, 0, stream>>>(bcount, bptr, gcursor, rowptr, N, B, E);
    kb_bin<<<nbin, 256, 0, stream>>>(ei, gcursor, pairs, E, B);

    k_att<<<(N * H + 255) / 256, 256, 0, stream>>>(h16, att_src, att_dst,
                                                   a_src, a_dst, N * H);

    kb_final<<<B, 256, 0, stream>>>(pairs, bptr, rowptr, col, N);

    k_pull<<<(N + 3) / 4, 256, 0, stream>>>(rowptr, col, h16, a_src,
                                            a_dst, bias, out, N);
}

// Round 3
// 450.241 us; speedup vs baseline: 1.6169x; 1.0028x over previous
//
#include <hip/hip_runtime.h>
#include <hip/hip_bf16.h>

#define H 8
#define C 16
#define HC 128          // H*C
#define NEG 0.2f
#define XS_S 132        // LDS row stride (floats) for k1 x-tile

#define BKT_SH 8        // 256 nodes per bucket
#define BKT_MSK 255
#define MAXB 1024       // supports N <= 262144 (src also packs into 18 bits)
#define EPB 4096        // edges per bin/hist block

// exact: for x>=0 max returns x, for x<0 returns 0.2x  (2 VALU, no cndmask)
__device__ __forceinline__ float lrelu(float x) { return fmaxf(x, NEG * x); }

__device__ __forceinline__ unsigned pack_bf16(float a, float b) {
    union { __hip_bfloat16 h; unsigned short u; } ua, ub;
    ua.h = __float2bfloat16(a);
    ub.h = __float2bfloat16(b);
    return (unsigned)ua.u | ((unsigned)ub.u << 16);
}
__device__ __forceinline__ float bf_lo(unsigned d) { return __uint_as_float(d << 16); }
__device__ __forceinline__ float bf_hi(unsigned d) { return __uint_as_float(d & 0xffff0000u); }

// K1: h = x @ W, fp32 register-tiled GEMM, bf16-packed output.
__global__ void __launch_bounds__(256) k1_gemm(const float* __restrict__ x,
                                               const float* __restrict__ W,
                                               unsigned* __restrict__ h16, int N) {
    __shared__ float xs[64 * XS_S];
    const int n0 = blockIdx.x * 64;
    const int t = threadIdx.x;
#pragma unroll
    for (int i = 0; i < 8; ++i) {
        int id = t + 256 * i;           // 2048 float4-chunks
        int r = id >> 5, kq = id & 31;
        int n = n0 + r;
        float4 v = (n < N) ? ((const float4*)x)[(size_t)n * 32 + kq]
                           : make_float4(0.f, 0.f, 0.f, 0.f);
        *(float4*)&xs[r * XS_S + kq * 4] = v;
    }
    __syncthreads();
    const int cg = t & 31;        // cols cg*4..+3
    const int r0 = (t >> 5) * 8;  // rows r0..r0+7
    float acc[8][4];
#pragma unroll
    for (int i = 0; i < 8; ++i)
#pragma unroll
        for (int j = 0; j < 4; ++j) acc[i][j] = 0.f;

#pragma unroll 4
    for (int k = 0; k < HC; ++k) {
        const float4 wv = ((const float4*)W)[k * 32 + cg];
        float wr[4] = {wv.x, wv.y, wv.z, wv.w};
#pragma unroll
        for (int i = 0; i < 8; ++i) {
            float xv = xs[(r0 + i) * XS_S + k];   // broadcast across cg lanes
#pragma unroll
            for (int j = 0; j < 4; ++j) acc[i][j] += xv * wr[j];
        }
    }
#pragma unroll
    for (int i = 0; i < 8; ++i) {
        int n = n0 + r0 + i;
        if (n < N) {
            uint2 dv = make_uint2(pack_bf16(acc[i][0], acc[i][1]),
                                  pack_bf16(acc[i][2], acc[i][3]));
            *(uint2*)&h16[(size_t)n * 64 + cg * 2] = dv;
        }
    }
}

// K_ATT: per-(node,head) attention logits from bf16 h.
__global__ void k_att(const unsigned* __restrict__ h16,
                      const float* __restrict__ att_src,
                      const float* __restrict__ att_dst,
                      float* __restrict__ a_src,
                      float* __restrict__ a_dst, int NH) {
    int idx = blockIdx.x * blockDim.x + threadIdx.x;
    if (idx >= NH) return;
    int n = idx >> 3, hd = idx & 7;
    float s = 0.f, d = 0.f;
#pragma unroll
    for (int c2 = 0; c2 < 8; ++c2) {
        unsigned dv = h16[(size_t)n * 64 + hd * 8 + c2];
        float h0 = bf_lo(dv), h1 = bf_hi(dv);
        s += h0 * att_src[hd * C + 2 * c2] + h1 * att_src[hd * C + 2 * c2 + 1];
        d += h0 * att_dst[hd * C + 2 * c2] + h1 * att_dst[hd * C + 2 * c2 + 1];
    }
    a_src[idx] = s;
    a_dst[idx] = d;
}

// ---- CSR build via bucketed counting sort (no far atomics) ----

// KH_BUCKET: per-block LDS histogram of dst>>BKT_SH, merged into bcount.
__global__ void __launch_bounds__(256) kh_bucket(const int* __restrict__ ei,
                                                 int* __restrict__ bcount,
                                                 int E, int B) {
    __shared__ int hist[MAXB];
    const int t = threadIdx.x;
    for (int i = t; i < B; i += 256) hist[i] = 0;
    __syncthreads();
    const int e0 = blockIdx.x * EPB;
    const int nE = min(EPB, E - e0);
    for (int i = t; i < nE; i += 256)
        atomicAdd(&hist[ei[E + e0 + i] >> BKT_SH], 1);
    __syncthreads();
    for (int i = t; i < B; i += 256)
        if (hist[i]) atomicAdd(&bcount[i], hist[i]);
}

// KSCAN_B: single-block scan of bucket counts -> bptr[0..B], init gcursor,
// and rowptr[N] = E.
__global__ void __launch_bounds__(1024) kscan_b(const int* __restrict__ bcount,
                                                int* __restrict__ bptr,
                                                int* __restrict__ gcursor,
                                                int* __restrict__ rowptr,
                                                int N, int B, int E) {
    __shared__ int s[MAXB];
    const int t = threadIdx.x;
    s[t] = (t < B) ? bcount[t] : 0;
    __syncthreads();
    for (int off = 1; off < MAXB; off <<= 1) {
        int v = (t >= off) ? s[t - off] : 0;
        __syncthreads();
        s[t] += v;
        __syncthreads();
    }
    if (t < B) {
        bptr[t + 1] = s[t];
        gcursor[t] = s[t] - bcount[t];   // exclusive base
    }
    if (t == 0) { bptr[0] = 0; rowptr[N] = E; }
}

// KB_BIN: partition edges into bucket-contiguous pairs[]. Each block builds an
// LDS histogram of its EPB-edge chunk, reserves per-bucket ranges with ONE
// global atomic per (block,bucket), then deposits packed (src | ldst<<18)
// via LDS cursors. Writes land in ~40-170 B runs per bucket -> line-friendly.
__global__ void __launch_bounds__(256) kb_bin(const int* __restrict__ ei,
                                              int* __restrict__ gcursor,
                                              unsigned* __restrict__ pairs,
                                              int E, int B) {
    __shared__ int hist[MAXB];
    __shared__ int lbase[MAXB];
    const int t = threadIdx.x;
    const int e0 = blockIdx.x * EPB;
    const int nE = min(EPB, E - e0);
    for (int i = t; i < B; i += 256) hist[i] = 0;
    __syncthreads();
    for (int i = t; i < nE; i += 256)
        atomicAdd(&hist[ei[E + e0 + i] >> BKT_SH], 1);
    __syncthreads();
    for (int i = t; i < B; i += 256) {
        int h = hist[i];
        if (h) lbase[i] = atomicAdd(&gcursor[i], h);
    }
    __syncthreads();
    for (int i = t; i < nE; i += 256) {
        int dst = ei[E + e0 + i];
        int src = ei[e0 + i];
        int b = dst >> BKT_SH;
        int pos = atomicAdd(&lbase[b], 1);
        pairs[pos] = (unsigned)src | ((unsigned)(dst & BKT_MSK) << 18);
    }
}

// KB_FINAL: one block per bucket. Count per-node degrees in LDS, scan in LDS
// (bucket-contiguity means rowptr[n] = bptr[b] + local_excl), write rowptr
// coalesced, then scatter col within the bucket's 32 KB L2-resident window
// using LDS cursors. No global atomics at all.
__global__ void __launch_bounds__(256) kb_final(const unsigned* __restrict__ pairs,
                                                const int* __restrict__ bptr,
                                                int* __restrict__ rowptr,
                                                int* __restrict__ col, int N) {
    __shared__ int cnt[256];
    __shared__ int incl[256];
    __shared__ int lcur[256];
    const int b = blockIdx.x;
    const int t = threadIdx.x;
    const int n0 = b << BKT_SH;
    const int jbeg = bptr[b], jend = bptr[b + 1];
    cnt[t] = 0;
    __syncthreads();
    for (int j = jbeg + t; j < jend; j += 256)
        atomicAdd(&cnt[pairs[j] >> 18], 1);
    __syncthreads();
    incl[t] = cnt[t];
    __syncthreads();
    for (int off = 1; off < 256; off <<= 1) {
        int v = (t >= off) ? incl[t - off] : 0;
        __syncthreads();
        incl[t] += v;
        __syncthreads();
    }
    const int base = jbeg + incl[t] - cnt[t];
    if (n0 + t < N) rowptr[n0 + t] = base;
    lcur[t] = base;
    __syncthreads();
    for (int j = jbeg + t; j < jend; j += 256) {
        unsigned v = pairs[j];
        int pos = atomicAdd(&lcur[v >> 18], 1);
        col[pos] = (int)(v & 0x3FFFF);
    }
}

// K_PULL: one wave per node, lane t owns channels {2t,2t+1}, head t>>3.
// Softmax numerator w computed ONCE per (edge,head): in the 4-edge unrolled
// body the 32 (edge,head) pairs map to lanes (lane l computes pair l&31),
// then each lane pulls its 4 w's via ds_bpermute with constant lane indices
// (LDS pipe, off the VALU). Bit-identical to per-lane recompute.
// All hot indices are 32-bit unsigned -> saddr-form loads, no 64-bit VALU.
__global__ void __launch_bounds__(256) k_pull(const int* __restrict__ rowptr,
                                              const int* __restrict__ col,
                                              const unsigned* __restrict__ h16,
                                              const float* __restrict__ a_src,
                                              const float* __restrict__ a_dst,
                                              const float* __restrict__ bias,
                                              float* __restrict__ out, int N) {
    const int node = blockIdx.x * 4 + (threadIdx.x >> 6);
    if (node >= N) return;
    const int t = threadIdx.x & 63;
    const int hd = t >> 3;          // this lane's head (channels 2t,2t+1)
    const int p = t & 31;           // pair id this lane computes in 4-groups
    const int eslot = p >> 3;       // edge slot 0..3
    const int hh = p & 7;           // head of the computed pair
    const int bidx = hd * 4;        // bpermute byte index for edge 0

    const float adst_own = a_dst[(unsigned)node * 8u + (unsigned)hd];
    const float adst_p   = a_dst[(unsigned)node * 8u + (unsigned)hh];
    const float wself = __expf(lrelu(a_src[(unsigned)node * 8u + (unsigned)hd] + adst_own));
    unsigned dself = h16[(unsigned)node * 64u + (unsigned)t];
    float a0 = bf_lo(dself) * wself, a1 = bf_hi(dself) * wself;
    float b0 = 0.f, b1 = 0.f, c0 = 0.f, c1 = 0.f, e0 = 0.f, e1 = 0.f;
    float sA = wself, sB = 0.f, sC = 0.f, sD = 0.f;

    const int beg = rowptr[node], end = rowptr[node + 1];
    int j = beg;
    for (; j + 4 <= end; j += 4) {
        int nA = col[j], nB = col[j + 1], nC = col[j + 2], nD = col[j + 3];
        int nP = eslot == 0 ? nA : eslot == 1 ? nB : eslot == 2 ? nC : nD;
        float wme = __expf(lrelu(a_src[(unsigned)nP * 8u + (unsigned)hh] + adst_p));
        int wi = __float_as_int(wme);
        float wA = __int_as_float(__builtin_amdgcn_ds_bpermute(bidx,      wi));
        float wB = __int_as_float(__builtin_amdgcn_ds_bpermute(bidx + 32, wi));
        float wC = __int_as_float(__builtin_amdgcn_ds_bpermute(bidx + 64, wi));
        float wD = __int_as_float(__builtin_amdgcn_ds_bpermute(bidx + 96, wi));
        unsigned dA = h16[(unsigned)nA * 64u + (unsigned)t];
        unsigned dB = h16[(unsigned)nB * 64u + (unsigned)t];
        unsigned dC = h16[(unsigned)nC * 64u + (unsigned)t];
        unsigned dD = h16[(unsigned)nD * 64u + (unsigned)t];
        a0 += bf_lo(dA) * wA; a1 += bf_hi(dA) * wA; sA += wA;
        b0 += bf_lo(dB) * wB; b1 += bf_hi(dB) * wB; sB += wB;
        c0 += bf_lo(dC) * wC; c1 += bf_hi(dC) * wC; sC += wC;
        e0 += bf_lo(dD) * wD; e1 += bf_hi(dD) * wD; sD += wD;
    }
    for (; j < end; ++j) {
        int nA = col[j];
        float wA = __expf(lrelu(a_src[(unsigned)nA * 8u + (unsigned)hd] + adst_own));
        unsigned dA = h16[(unsigned)nA * 64u + (unsigned)t];
        a0 += bf_lo(dA) * wA; a1 += bf_hi(dA) * wA; sA += wA;
    }
    const float s = sA + sB + sC + sD;
    const float inv = 1.f / (s + 1e-16f);
    const float acc0 = a0 + b0 + c0 + e0;
    const float acc1 = a1 + b1 + c1 + e1;
    const float2 bv = ((const float2*)bias)[t];
    float2 o;
    o.x = acc0 * inv + bv.x;
    o.y = acc1 * inv + bv.y;
    ((float2*)out)[(unsigned)node * 64u + (unsigned)t] = o;
}

extern "C" void kernel_launch(void* const* d_in, const int* in_sizes, int n_in,
                              void* d_out, int out_size, void* d_ws, size_t ws_size,
                              hipStream_t stream) {
    const float* x       = (const float*)d_in[0];
    const int*   ei      = (const int*)d_in[1];
    const float* W       = (const float*)d_in[2];
    const float* att_src = (const float*)d_in[3];
    const float* att_dst = (const float*)d_in[4];
    const float* bias    = (const float*)d_in[5];
    float* out = (float*)d_out;

    const int N = in_sizes[0] / HC;
    const int E = in_sizes[1] / 2;
    const int B = (N + BKT_MSK) >> BKT_SH;     // buckets of 256 nodes (<= MAXB)
    const int nbin = (E + EPB - 1) / EPB;

    // ws: h16[N*64]u32 | a_src[N*8]f | a_dst[N*8]f | bcount[MAXB] |
    //     bptr[MAXB+1] | gcursor[MAXB] | rowptr[N+1] | col[E] | pairs[E]
    unsigned* h16 = (unsigned*)d_ws;
    float* a_src  = (float*)(h16 + (size_t)N * 64);
    float* a_dst  = a_src + (size_t)N * H;
    int* bcount   = (int*)(a_dst + (size_t)N * H);
    int* bptr     = bcount + MAXB;
    int* gcursor  = bptr + (MAXB + 1);
    int* rowptr   = gcursor + MAXB;
    int* col      = rowptr + (N + 1);
    unsigned* pairs = (unsigned*)(col + E);

    (void)hipMemsetAsync(bcount, 0, MAXB * sizeof(int), stream);

    k1_gemm<<<(N + 63) / 64, 256, 0, stream>>>(x, W, h16, N);

    kh_bucket<<<nbin, 256, 0, stream>>>(ei, bcount, E, B);
    kscan_b<<<1, 1024, 0, stream>>>(bcount, bptr, gcursor, rowptr, N, B, E);
    kb_bin<<<nbin, 256, 0, stream>>>(ei, gcursor, pairs, E, B);

    k_att<<<(N * H + 255) / 256, 256, 0, stream>>>(h16, att_src, att_dst,
                                                   a_src, a_dst, N * H);

    kb_final<<<B, 256, 0, stream>>>(pairs, bptr, rowptr, col, N);

    k_pull<<<(N + 3) / 4, 256, 0, stream>>>(rowptr, col, h16, a_src,
                                            a_dst, bias, out, N);
}

// Round 4
// 437.629 us; speedup vs baseline: 1.6635x; 1.0288x over previous
//
#include <hip/hip_runtime.h>
#include <hip/hip_bf16.h>

#define H 8
#define C 16
#define HC 128          // H*C
#define NEG 0.2f
#define XS_S 132        // LDS row stride (floats) for k1 x-tile

#define BKT_SH 8        // 256 nodes per bucket
#define BKT_MSK 255
#define MAXB 1024       // supports N <= 262144 (src also packs into 18 bits)
#define EPB 4096        // edges per bin/hist block

// exact: for x>=0 max returns x, for x<0 returns 0.2x  (2 VALU, no cndmask)
__device__ __forceinline__ float lrelu(float x) { return fmaxf(x, NEG * x); }

__device__ __forceinline__ unsigned pack_bf16(float a, float b) {
    union { __hip_bfloat16 h; unsigned short u; } ua, ub;
    ua.h = __float2bfloat16(a);
    ub.h = __float2bfloat16(b);
    return (unsigned)ua.u | ((unsigned)ub.u << 16);
}
__device__ __forceinline__ float bf_lo(unsigned d) { return __uint_as_float(d << 16); }
__device__ __forceinline__ float bf_hi(unsigned d) { return __uint_as_float(d & 0xffff0000u); }

// K1: h = x @ W, fp32 register-tiled GEMM, bf16-packed output.
// Epilogue additionally computes a_src/a_dst from the fp32 accumulators
// (width-4 shfl reduce across the 4 lanes holding one head's 16 cols),
// replacing the separate k_att pass.
__global__ void __launch_bounds__(256) k1_gemm(const float* __restrict__ x,
                                               const float* __restrict__ W,
                                               const float* __restrict__ att_src,
                                               const float* __restrict__ att_dst,
                                               unsigned* __restrict__ h16,
                                               float* __restrict__ a_src,
                                               float* __restrict__ a_dst, int N) {
    __shared__ float xs[64 * XS_S];
    const int n0 = blockIdx.x * 64;
    const int t = threadIdx.x;
#pragma unroll
    for (int i = 0; i < 8; ++i) {
        int id = t + 256 * i;           // 2048 float4-chunks
        int r = id >> 5, kq = id & 31;
        int n = n0 + r;
        float4 v = (n < N) ? ((const float4*)x)[(size_t)n * 32 + kq]
                           : make_float4(0.f, 0.f, 0.f, 0.f);
        *(float4*)&xs[r * XS_S + kq * 4] = v;
    }
    __syncthreads();
    const int cg = t & 31;        // cols cg*4..+3
    const int r0 = (t >> 5) * 8;  // rows r0..r0+7
    float acc[8][4];
#pragma unroll
    for (int i = 0; i < 8; ++i)
#pragma unroll
        for (int j = 0; j < 4; ++j) acc[i][j] = 0.f;

#pragma unroll 4
    for (int k = 0; k < HC; ++k) {
        const float4 wv = ((const float4*)W)[k * 32 + cg];
        float wr[4] = {wv.x, wv.y, wv.z, wv.w};
#pragma unroll
        for (int i = 0; i < 8; ++i) {
            float xv = xs[(r0 + i) * XS_S + k];   // broadcast across cg lanes
#pragma unroll
            for (int j = 0; j < 4; ++j) acc[i][j] += xv * wr[j];
        }
    }
    const int fhd = cg >> 2;       // head owning this lane's 4 cols
    const int cq  = cg & 3;        // quarter within the head's 16 cols
#pragma unroll
    for (int i = 0; i < 8; ++i) {
        int n = n0 + r0 + i;
        if (n < N) {
            uint2 dv = make_uint2(pack_bf16(acc[i][0], acc[i][1]),
                                  pack_bf16(acc[i][2], acc[i][3]));
            *(uint2*)&h16[(size_t)n * 64 + cg * 2] = dv;
        }
        float ps = 0.f, pd = 0.f;
#pragma unroll
        for (int jj = 0; jj < 4; ++jj) {
            float hv = acc[i][jj];
            ps += hv * att_src[fhd * C + cq * 4 + jj];
            pd += hv * att_dst[fhd * C + cq * 4 + jj];
        }
        ps += __shfl_xor(ps, 1, 4); pd += __shfl_xor(pd, 1, 4);
        ps += __shfl_xor(ps, 2, 4); pd += __shfl_xor(pd, 2, 4);
        if (cq == 0 && n < N) {
            a_src[(unsigned)n * 8u + fhd] = ps;
            a_dst[(unsigned)n * 8u + fhd] = pd;
        }
    }
}

// ---- CSR build via bucketed counting sort (no far atomics) ----

// KH_BUCKET: per-block LDS histogram of dst>>BKT_SH, merged into bcount.
__global__ void __launch_bounds__(256) kh_bucket(const int* __restrict__ ei,
                                                 int* __restrict__ bcount,
                                                 int E, int B) {
    __shared__ int hist[MAXB];
    const int t = threadIdx.x;
    for (int i = t; i < B; i += 256) hist[i] = 0;
    __syncthreads();
    const int e0 = blockIdx.x * EPB;
    const int nE = min(EPB, E - e0);
    for (int i = t; i < nE; i += 256)
        atomicAdd(&hist[ei[E + e0 + i] >> BKT_SH], 1);
    __syncthreads();
    for (int i = t; i < B; i += 256)
        if (hist[i]) atomicAdd(&bcount[i], hist[i]);
}

// KSCAN_B: single-block scan of bucket counts -> bptr[0..B], init gcursor,
// and rowptr[N] = E.
__global__ void __launch_bounds__(1024) kscan_b(const int* __restrict__ bcount,
                                                int* __restrict__ bptr,
                                                int* __restrict__ gcursor,
                                                int* __restrict__ rowptr,
                                                int N, int B, int E) {
    __shared__ int s[MAXB];
    const int t = threadIdx.x;
    s[t] = (t < B) ? bcount[t] : 0;
    __syncthreads();
    for (int off = 1; off < MAXB; off <<= 1) {
        int v = (t >= off) ? s[t - off] : 0;
        __syncthreads();
        s[t] += v;
        __syncthreads();
    }
    if (t < B) {
        bptr[t + 1] = s[t];
        gcursor[t] = s[t] - bcount[t];   // exclusive base
    }
    if (t == 0) { bptr[0] = 0; rowptr[N] = E; }
}

// KB_BIN: partition edges into bucket-contiguous pairs[]. Each block builds an
// LDS histogram of its EPB-edge chunk, reserves per-bucket ranges with ONE
// global atomic per (block,bucket), then deposits packed (src | ldst<<18)
// via LDS cursors. Writes land in ~40-170 B runs per bucket -> line-friendly.
__global__ void __launch_bounds__(256) kb_bin(const int* __restrict__ ei,
                                              int* __restrict__ gcursor,
                                              unsigned* __restrict__ pairs,
                                              int E, int B) {
    __shared__ int hist[MAXB];
    __shared__ int lbase[MAXB];
    const int t = threadIdx.x;
    const int e0 = blockIdx.x * EPB;
    const int nE = min(EPB, E - e0);
    for (int i = t; i < B; i += 256) hist[i] = 0;
    __syncthreads();
    for (int i = t; i < nE; i += 256)
        atomicAdd(&hist[ei[E + e0 + i] >> BKT_SH], 1);
    __syncthreads();
    for (int i = t; i < B; i += 256) {
        int h = hist[i];
        if (h) lbase[i] = atomicAdd(&gcursor[i], h);
    }
    __syncthreads();
    for (int i = t; i < nE; i += 256) {
        int dst = ei[E + e0 + i];
        int src = ei[e0 + i];
        int b = dst >> BKT_SH;
        int pos = atomicAdd(&lbase[b], 1);
        pairs[pos] = (unsigned)src | ((unsigned)(dst & BKT_MSK) << 18);
    }
}

// KB_FINAL: one block per bucket. Count per-node degrees in LDS, scan in LDS
// (bucket-contiguity means rowptr[n] = bptr[b] + local_excl), write rowptr
// coalesced, then scatter col within the bucket's 32 KB L2-resident window
// using LDS cursors. No global atomics at all.
__global__ void __launch_bounds__(256) kb_final(const unsigned* __restrict__ pairs,
                                                const int* __restrict__ bptr,
                                                int* __restrict__ rowptr,
                                                int* __restrict__ col, int N) {
    __shared__ int cnt[256];
    __shared__ int incl[256];
    __shared__ int lcur[256];
    const int b = blockIdx.x;
    const int t = threadIdx.x;
    const int n0 = b << BKT_SH;
    const int jbeg = bptr[b], jend = bptr[b + 1];
    cnt[t] = 0;
    __syncthreads();
    for (int j = jbeg + t; j < jend; j += 256)
        atomicAdd(&cnt[pairs[j] >> 18], 1);
    __syncthreads();
    incl[t] = cnt[t];
    __syncthreads();
    for (int off = 1; off < 256; off <<= 1) {
        int v = (t >= off) ? incl[t - off] : 0;
        __syncthreads();
        incl[t] += v;
        __syncthreads();
    }
    const int base = jbeg + incl[t] - cnt[t];
    if (n0 + t < N) rowptr[n0 + t] = base;
    lcur[t] = base;
    __syncthreads();
    for (int j = jbeg + t; j < jend; j += 256) {
        unsigned v = pairs[j];
        int pos = atomicAdd(&lcur[v >> 18], 1);
        col[pos] = (int)(v & 0x3FFFF);
    }
}

// K_PULL: one wave per node, lane t owns channels {2t,2t+1}, head t>>3.
// 8-edge unrolled body: the 64 (edge,head) pairs of an 8-edge group map 1:1
// onto the wave (lane l computes pair (l>>3, l&7)); w distributed to the
// consuming lanes via ds_bpermute with compile-time lane indices. Doubles
// per-wave memory-level parallelism vs the 4-wide version (latency-bound).
__global__ void __launch_bounds__(256) k_pull(const int* __restrict__ rowptr,
                                              const int* __restrict__ col,
                                              const unsigned* __restrict__ h16,
                                              const float* __restrict__ a_src,
                                              const float* __restrict__ a_dst,
                                              const float* __restrict__ bias,
                                              float* __restrict__ out, int N) {
    const int node = blockIdx.x * 4 + (threadIdx.x >> 6);
    if (node >= N) return;
    const int t = threadIdx.x & 63;
    const int hd = t >> 3;          // this lane's head (channels 2t,2t+1)
    const int hh = t & 7;           // head of the pair this lane computes
    const int bidx = hd * 4;        // bpermute byte index, edge slot 0

    const float adst_own = a_dst[(unsigned)node * 8u + (unsigned)hd];
    const float adst_hh  = a_dst[(unsigned)node * 8u + (unsigned)hh];
    const float wself = __expf(lrelu(a_src[(unsigned)node * 8u + (unsigned)hd] + adst_own));
    unsigned dself = h16[(unsigned)node * 64u + (unsigned)t];
    float a0 = bf_lo(dself) * wself, a1 = bf_hi(dself) * wself;
    float b0 = 0.f, b1 = 0.f, c0 = 0.f, c1 = 0.f, e0 = 0.f, e1 = 0.f;
    float sA = wself, sB = 0.f, sC = 0.f, sD = 0.f;

    const int beg = rowptr[node], end = rowptr[node + 1];
    int j = beg;
    for (; j + 8 <= end; j += 8) {
        int n0_ = col[j],     n1 = col[j + 1], n2 = col[j + 2], n3 = col[j + 3];
        int n4  = col[j + 4], n5 = col[j + 5], n6 = col[j + 6], n7 = col[j + 7];
        int nP = col[j + (t >> 3)];       // 32 B window, single line
        float wme = __expf(lrelu(a_src[(unsigned)nP * 8u + (unsigned)hh] + adst_hh));
        int wi = __float_as_int(wme);
        float w0 = __int_as_float(__builtin_amdgcn_ds_bpermute(bidx,       wi));
        float w1 = __int_as_float(__builtin_amdgcn_ds_bpermute(bidx + 32,  wi));
        float w2 = __int_as_float(__builtin_amdgcn_ds_bpermute(bidx + 64,  wi));
        float w3 = __int_as_float(__builtin_amdgcn_ds_bpermute(bidx + 96,  wi));
        float w4 = __int_as_float(__builtin_amdgcn_ds_bpermute(bidx + 128, wi));
        float w5 = __int_as_float(__builtin_amdgcn_ds_bpermute(bidx + 160, wi));
        float w6 = __int_as_float(__builtin_amdgcn_ds_bpermute(bidx + 192, wi));
        float w7 = __int_as_float(__builtin_amdgcn_ds_bpermute(bidx + 224, wi));
        unsigned d0 = h16[(unsigned)n0_ * 64u + (unsigned)t];
        unsigned d1 = h16[(unsigned)n1 * 64u + (unsigned)t];
        unsigned d2 = h16[(unsigned)n2 * 64u + (unsigned)t];
        unsigned d3 = h16[(unsigned)n3 * 64u + (unsigned)t];
        unsigned d4 = h16[(unsigned)n4 * 64u + (unsigned)t];
        unsigned d5 = h16[(unsigned)n5 * 64u + (unsigned)t];
        unsigned d6 = h16[(unsigned)n6 * 64u + (unsigned)t];
        unsigned d7 = h16[(unsigned)n7 * 64u + (unsigned)t];
        a0 += bf_lo(d0) * w0; a1 += bf_hi(d0) * w0; sA += w0;
        b0 += bf_lo(d1) * w1; b1 += bf_hi(d1) * w1; sB += w1;
        c0 += bf_lo(d2) * w2; c1 += bf_hi(d2) * w2; sC += w2;
        e0 += bf_lo(d3) * w3; e1 += bf_hi(d3) * w3; sD += w3;
        a0 += bf_lo(d4) * w4; a1 += bf_hi(d4) * w4; sA += w4;
        b0 += bf_lo(d5) * w5; b1 += bf_hi(d5) * w5; sB += w5;
        c0 += bf_lo(d6) * w6; c1 += bf_hi(d6) * w6; sC += w6;
        e0 += bf_lo(d7) * w7; e1 += bf_hi(d7) * w7; sD += w7;
    }
    if (j + 4 <= end) {   // 4-wide tail: 32-lane pair compute (upper half dups)
        int n0_ = col[j], n1 = col[j + 1], n2 = col[j + 2], n3 = col[j + 3];
        int nP = col[j + ((t >> 3) & 3)];
        float wme = __expf(lrelu(a_src[(unsigned)nP * 8u + (unsigned)hh] + adst_hh));
        int wi = __float_as_int(wme);
        float w0 = __int_as_float(__builtin_amdgcn_ds_bpermute(bidx,      wi));
        float w1 = __int_as_float(__builtin_amdgcn_ds_bpermute(bidx + 32, wi));
        float w2 = __int_as_float(__builtin_amdgcn_ds_bpermute(bidx + 64, wi));
        float w3 = __int_as_float(__builtin_amdgcn_ds_bpermute(bidx + 96, wi));
        unsigned d0 = h16[(unsigned)n0_ * 64u + (unsigned)t];
        unsigned d1 = h16[(unsigned)n1 * 64u + (unsigned)t];
        unsigned d2 = h16[(unsigned)n2 * 64u + (unsigned)t];
        unsigned d3 = h16[(unsigned)n3 * 64u + (unsigned)t];
        a0 += bf_lo(d0) * w0; a1 += bf_hi(d0) * w0; sA += w0;
        b0 += bf_lo(d1) * w1; b1 += bf_hi(d1) * w1; sB += w1;
        c0 += bf_lo(d2) * w2; c1 += bf_hi(d2) * w2; sC += w2;
        e0 += bf_lo(d3) * w3; e1 += bf_hi(d3) * w3; sD += w3;
        j += 4;
    }
    for (; j < end; ++j) {
        int nA = col[j];
        float wA = __expf(lrelu(a_src[(unsigned)nA * 8u + (unsigned)hd] + adst_own));
        unsigned dA = h16[(unsigned)nA * 64u + (unsigned)t];
        a0 += bf_lo(dA) * wA; a1 += bf_hi(dA) * wA; sA += wA;
    }
    const float s = sA + sB + sC + sD;
    const float inv = 1.f / (s + 1e-16f);
    const float acc0 = a0 + b0 + c0 + e0;
    const float acc1 = a1 + b1 + c1 + e1;
    const float2 bv = ((const float2*)bias)[t];
    float2 o;
    o.x = acc0 * inv + bv.x;
    o.y = acc1 * inv + bv.y;
    ((float2*)out)[(unsigned)node * 64u + (unsigned)t] = o;
}

extern "C" void kernel_launch(void* const* d_in, const int* in_sizes, int n_in,
                              void* d_out, int out_size, void* d_ws, size_t ws_size,
                              hipStream_t stream) {
    const float* x       = (const float*)d_in[0];
    const int*   ei      = (const int*)d_in[1];
    const float* W       = (const float*)d_in[2];
    const float* att_src = (const float*)d_in[3];
    const float* att_dst = (const float*)d_in[4];
    const float* bias    = (const float*)d_in[5];
    float* out = (float*)d_out;

    const int N = in_sizes[0] / HC;
    const int E = in_sizes[1] / 2;
    const int B = (N + BKT_MSK) >> BKT_SH;     // buckets of 256 nodes (<= MAXB)
    const int nbin = (E + EPB - 1) / EPB;

    // ws: h16[N*64]u32 | a_src[N*8]f | a_dst[N*8]f | bcount[MAXB] |
    //     bptr[MAXB+1] | gcursor[MAXB] | rowptr[N+1] | col[E] | pairs[E]
    unsigned* h16 = (unsigned*)d_ws;
    float* a_src  = (float*)(h16 + (size_t)N * 64);
    float* a_dst  = a_src + (size_t)N * H;
    int* bcount   = (int*)(a_dst + (size_t)N * H);
    int* bptr     = bcount + MAXB;
    int* gcursor  = bptr + (MAXB + 1);
    int* rowptr   = gcursor + MAXB;
    int* col      = rowptr + (N + 1);
    unsigned* pairs = (unsigned*)(col + E);

    (void)hipMemsetAsync(bcount, 0, MAXB * sizeof(int), stream);

    k1_gemm<<<(N + 63) / 64, 256, 0, stream>>>(x, W, att_src, att_dst,
                                               h16, a_src, a_dst, N);

    kh_bucket<<<nbin, 256, 0, stream>>>(ei, bcount, E, B);
    kscan_b<<<1, 1024, 0, stream>>>(bcount, bptr, gcursor, rowptr, N, B, E);
    kb_bin<<<nbin, 256, 0, stream>>>(ei, gcursor, pairs, E, B);
    kb_final<<<B, 256, 0, stream>>>(pairs, bptr, rowptr, col, N);

    k_pull<<<(N + 3) / 4, 256, 0, stream>>>(rowptr, col, h16, a_src,
                                            a_dst, bias, out, N);
}

// Round 5
// 436.519 us; speedup vs baseline: 1.6678x; 1.0025x over previous
//
#include <hip/hip_runtime.h>
#include <hip/hip_bf16.h>

#define H 8
#define C 16
#define HC 128          // H*C
#define NEG 0.2f
#define XS_S 132        // LDS row stride (floats) for k1 x-tile

#define BKT_SH 8        // 256 nodes per bucket
#define BKT_MSK 255
#define MAXB 1024       // supports N <= 262144 (src also packs into 18 bits)
#define EPB 4096        // edges per bin/hist block

// exact: for x>=0 max returns x, for x<0 returns 0.2x  (2 VALU, no cndmask)
__device__ __forceinline__ float lrelu(float x) { return fmaxf(x, NEG * x); }

__device__ __forceinline__ unsigned pack_bf16(float a, float b) {
    union { __hip_bfloat16 h; unsigned short u; } ua, ub;
    ua.h = __float2bfloat16(a);
    ub.h = __float2bfloat16(b);
    return (unsigned)ua.u | ((unsigned)ub.u << 16);
}
__device__ __forceinline__ float bf_lo(unsigned d) { return __uint_as_float(d << 16); }
__device__ __forceinline__ float bf_hi(unsigned d) { return __uint_as_float(d & 0xffff0000u); }

// K1: h = x @ W, fp32 register-tiled GEMM, bf16-packed output.
// Epilogue also computes a_src/a_dst from the fp32 accumulators
// (width-4 shfl reduce), replacing a separate k_att pass.
__global__ void __launch_bounds__(256) k1_gemm(const float* __restrict__ x,
                                               const float* __restrict__ W,
                                               const float* __restrict__ att_src,
                                               const float* __restrict__ att_dst,
                                               unsigned* __restrict__ h16,
                                               float* __restrict__ a_src,
                                               float* __restrict__ a_dst, int N) {
    __shared__ float xs[64 * XS_S];
    const int n0 = blockIdx.x * 64;
    const int t = threadIdx.x;
#pragma unroll
    for (int i = 0; i < 8; ++i) {
        int id = t + 256 * i;           // 2048 float4-chunks
        int r = id >> 5, kq = id & 31;
        int n = n0 + r;
        float4 v = (n < N) ? ((const float4*)x)[(size_t)n * 32 + kq]
                           : make_float4(0.f, 0.f, 0.f, 0.f);
        *(float4*)&xs[r * XS_S + kq * 4] = v;
    }
    __syncthreads();
    const int cg = t & 31;        // cols cg*4..+3
    const int r0 = (t >> 5) * 8;  // rows r0..r0+7
    float acc[8][4];
#pragma unroll
    for (int i = 0; i < 8; ++i)
#pragma unroll
        for (int j = 0; j < 4; ++j) acc[i][j] = 0.f;

#pragma unroll 4
    for (int k = 0; k < HC; ++k) {
        const float4 wv = ((const float4*)W)[k * 32 + cg];
        float wr[4] = {wv.x, wv.y, wv.z, wv.w};
#pragma unroll
        for (int i = 0; i < 8; ++i) {
            float xv = xs[(r0 + i) * XS_S + k];   // broadcast across cg lanes
#pragma unroll
            for (int j = 0; j < 4; ++j) acc[i][j] += xv * wr[j];
        }
    }
    const int fhd = cg >> 2;       // head owning this lane's 4 cols
    const int cq  = cg & 3;        // quarter within the head's 16 cols
#pragma unroll
    for (int i = 0; i < 8; ++i) {
        int n = n0 + r0 + i;
        if (n < N) {
            uint2 dv = make_uint2(pack_bf16(acc[i][0], acc[i][1]),
                                  pack_bf16(acc[i][2], acc[i][3]));
            *(uint2*)&h16[(size_t)n * 64 + cg * 2] = dv;
        }
        float ps = 0.f, pd = 0.f;
#pragma unroll
        for (int jj = 0; jj < 4; ++jj) {
            float hv = acc[i][jj];
            ps += hv * att_src[fhd * C + cq * 4 + jj];
            pd += hv * att_dst[fhd * C + cq * 4 + jj];
        }
        ps += __shfl_xor(ps, 1, 4); pd += __shfl_xor(pd, 1, 4);
        ps += __shfl_xor(ps, 2, 4); pd += __shfl_xor(pd, 2, 4);
        if (cq == 0 && n < N) {
            a_src[(unsigned)n * 8u + fhd] = ps;
            a_dst[(unsigned)n * 8u + fhd] = pd;
        }
    }
}

// ---- CSR build via bucketed counting sort (no far atomics) ----

// KH_BUCKET: per-block LDS histogram of dst>>BKT_SH, merged into bcount.
__global__ void __launch_bounds__(256) kh_bucket(const int* __restrict__ ei,
                                                 int* __restrict__ bcount,
                                                 int E, int B) {
    __shared__ int hist[MAXB];
    const int t = threadIdx.x;
    for (int i = t; i < B; i += 256) hist[i] = 0;
    __syncthreads();
    const int e0 = blockIdx.x * EPB;
    const int nE = min(EPB, E - e0);
    if ((E & 3) == 0) {
        const int nE4 = nE >> 2;
        const int4* d4p = (const int4*)(ei + E + e0);
        for (int i = t; i < nE4; i += 256) {
            int4 d = d4p[i];
            atomicAdd(&hist[d.x >> BKT_SH], 1);
            atomicAdd(&hist[d.y >> BKT_SH], 1);
            atomicAdd(&hist[d.z >> BKT_SH], 1);
            atomicAdd(&hist[d.w >> BKT_SH], 1);
        }
        for (int i = (nE4 << 2) + t; i < nE; i += 256)
            atomicAdd(&hist[ei[E + e0 + i] >> BKT_SH], 1);
    } else {
        for (int i = t; i < nE; i += 256)
            atomicAdd(&hist[ei[E + e0 + i] >> BKT_SH], 1);
    }
    __syncthreads();
    for (int i = t; i < B; i += 256)
        if (hist[i]) atomicAdd(&bcount[i], hist[i]);
}

// KSCAN_B: single-block scan of bucket counts -> bptr[0..B], init gcursor,
// and rowptr[N] = E.
__global__ void __launch_bounds__(1024) kscan_b(const int* __restrict__ bcount,
                                                int* __restrict__ bptr,
                                                int* __restrict__ gcursor,
                                                int* __restrict__ rowptr,
                                                int N, int B, int E) {
    __shared__ int s[MAXB];
    const int t = threadIdx.x;
    s[t] = (t < B) ? bcount[t] : 0;
    __syncthreads();
    for (int off = 1; off < MAXB; off <<= 1) {
        int v = (t >= off) ? s[t - off] : 0;
        __syncthreads();
        s[t] += v;
        __syncthreads();
    }
    if (t < B) {
        bptr[t + 1] = s[t];
        gcursor[t] = s[t] - bcount[t];   // exclusive base
    }
    if (t == 0) { bptr[0] = 0; rowptr[N] = E; }
}

// KB_BIN: partition edges into bucket-contiguous pairs[]. LDS histogram per
// chunk, ONE global atomic per (block,bucket) to reserve ranges, then deposit
// packed (src | ldst<<18) via LDS cursors.
__global__ void __launch_bounds__(256) kb_bin(const int* __restrict__ ei,
                                              int* __restrict__ gcursor,
                                              unsigned* __restrict__ pairs,
                                              int E, int B) {
    __shared__ int hist[MAXB];
    __shared__ int lbase[MAXB];
    const int t = threadIdx.x;
    const int e0 = blockIdx.x * EPB;
    const int nE = min(EPB, E - e0);
    for (int i = t; i < B; i += 256) hist[i] = 0;
    __syncthreads();
    const bool v4 = ((E & 3) == 0);
    const int nE4 = v4 ? (nE >> 2) : 0;
    const int4* d4p = (const int4*)(ei + E + e0);
    const int4* s4p = (const int4*)(ei + e0);
    if (v4) {
        for (int i = t; i < nE4; i += 256) {
            int4 d = d4p[i];
            atomicAdd(&hist[d.x >> BKT_SH], 1);
            atomicAdd(&hist[d.y >> BKT_SH], 1);
            atomicAdd(&hist[d.z >> BKT_SH], 1);
            atomicAdd(&hist[d.w >> BKT_SH], 1);
        }
        for (int i = (nE4 << 2) + t; i < nE; i += 256)
            atomicAdd(&hist[ei[E + e0 + i] >> BKT_SH], 1);
    } else {
        for (int i = t; i < nE; i += 256)
            atomicAdd(&hist[ei[E + e0 + i] >> BKT_SH], 1);
    }
    __syncthreads();
    for (int i = t; i < B; i += 256) {
        int h = hist[i];
        if (h) lbase[i] = atomicAdd(&gcursor[i], h);
    }
    __syncthreads();
    if (v4) {
        for (int i = t; i < nE4; i += 256) {
            int4 d = d4p[i];
            int4 sv = s4p[i];
#pragma unroll
            for (int q = 0; q < 4; ++q) {
                int dst = (&d.x)[q], src = (&sv.x)[q];
                int b = dst >> BKT_SH;
                int pos = atomicAdd(&lbase[b], 1);
                pairs[pos] = (unsigned)src | ((unsigned)(dst & BKT_MSK) << 18);
            }
        }
        for (int i = (nE4 << 2) + t; i < nE; i += 256) {
            int dst = ei[E + e0 + i], src = ei[e0 + i];
            int b = dst >> BKT_SH;
            int pos = atomicAdd(&lbase[b], 1);
            pairs[pos] = (unsigned)src | ((unsigned)(dst & BKT_MSK) << 18);
        }
    } else {
        for (int i = t; i < nE; i += 256) {
            int dst = ei[E + e0 + i], src = ei[e0 + i];
            int b = dst >> BKT_SH;
            int pos = atomicAdd(&lbase[b], 1);
            pairs[pos] = (unsigned)src | ((unsigned)(dst & BKT_MSK) << 18);
        }
    }
}

// KB_FINAL: one block per bucket. Per-node counts + scan in LDS, rowptr
// coalesced, scatter col in the bucket's L2-resident window via LDS cursors.
__global__ void __launch_bounds__(256) kb_final(const unsigned* __restrict__ pairs,
                                                const int* __restrict__ bptr,
                                                int* __restrict__ rowptr,
                                                int* __restrict__ col, int N) {
    __shared__ int cnt[256];
    __shared__ int incl[256];
    __shared__ int lcur[256];
    const int b = blockIdx.x;
    const int t = threadIdx.x;
    const int n0 = b << BKT_SH;
    const int jbeg = bptr[b], jend = bptr[b + 1];
    cnt[t] = 0;
    __syncthreads();
    for (int j = jbeg + t; j < jend; j += 256)
        atomicAdd(&cnt[pairs[j] >> 18], 1);
    __syncthreads();
    incl[t] = cnt[t];
    __syncthreads();
    for (int off = 1; off < 256; off <<= 1) {
        int v = (t >= off) ? incl[t - off] : 0;
        __syncthreads();
        incl[t] += v;
        __syncthreads();
    }
    const int base = jbeg + incl[t] - cnt[t];
    if (n0 + t < N) rowptr[n0 + t] = base;
    lcur[t] = base;
    __syncthreads();
    for (int j = jbeg + t; j < jend; j += 256) {
        unsigned v = pairs[j];
        int pos = atomicAdd(&lcur[v >> 18], 1);
        col[pos] = (int)(v & 0x3FFFF);
    }
}

// K_PULL: one wave per node. Lane map: slot = t>>5 (2 edge slots),
// cc = t&31 (4 channels: cols 4cc..4cc+3), head hh2 = cc>>2.
// uint2 h-loads halve unpack/addr work vs the 2-ch/lane version; per 8-edge
// group, lane l computes w for pair (edge l>>3, head l&7) once, consumers
// fetch via ds_bpermute (4 per group instead of 8). Epilogue: one
// shfl_xor(32) pair-reduce + coalesced float4 store.
__global__ void __launch_bounds__(256) k_pull(const int* __restrict__ rowptr,
                                              const int* __restrict__ col,
                                              const unsigned* __restrict__ h16,
                                              const float* __restrict__ a_src,
                                              const float* __restrict__ a_dst,
                                              const float* __restrict__ bias,
                                              float* __restrict__ out, int N) {
    const int node = blockIdx.x * 4 + (threadIdx.x >> 6);
    if (node >= N) return;
    const int t = threadIdx.x & 63;
    const int slot = t >> 5;
    const int cc = t & 31;
    const int hh2 = cc >> 2;      // head this lane accumulates
    const int hw = t & 7;         // head this lane computes w for

    const float adst_c = a_dst[(unsigned)node * 8u + (unsigned)hh2];
    const float adst_w = a_dst[(unsigned)node * 8u + (unsigned)hw];

    float f0 = 0.f, f1 = 0.f, f2 = 0.f, f3 = 0.f, s = 0.f;
    if (slot == 0) {   // self loop counted once
        const float wself = __expf(lrelu(a_src[(unsigned)node * 8u + (unsigned)hh2] + adst_c));
        uint2 d = *(const uint2*)&h16[(unsigned)node * 64u + (unsigned)cc * 2u];
        f0 = bf_lo(d.x) * wself; f1 = bf_hi(d.x) * wself;
        f2 = bf_lo(d.y) * wself; f3 = bf_hi(d.y) * wself;
        s = wself;
    }

    const int beg = rowptr[node], end = rowptr[node + 1];
    int j = beg;
    for (; j + 8 <= end; j += 8) {
        int nP = col[j + (t >> 3)];
        float wme = __expf(lrelu(a_src[(unsigned)nP * 8u + (unsigned)hw] + adst_w));
        int wi = __float_as_int(wme);
#pragma unroll
        for (int k = 0; k < 4; ++k) {
            const int e = slot + 2 * k;     // this lane's edge this step
            int ne = col[j + e];
            float w = __int_as_float(
                __builtin_amdgcn_ds_bpermute((e * 8 + hh2) * 4, wi));
            uint2 d = *(const uint2*)&h16[(unsigned)ne * 64u + (unsigned)cc * 2u];
            f0 += bf_lo(d.x) * w; f1 += bf_hi(d.x) * w;
            f2 += bf_lo(d.y) * w; f3 += bf_hi(d.y) * w;
            s += w;
        }
    }
    for (; j < end; ++j) {
        if (slot == 0) {   // tail: lower half only (no double count)
            int ne = col[j];
            float w = __expf(lrelu(a_src[(unsigned)ne * 8u + (unsigned)hh2] + adst_c));
            uint2 d = *(const uint2*)&h16[(unsigned)ne * 64u + (unsigned)cc * 2u];
            f0 += bf_lo(d.x) * w; f1 += bf_hi(d.x) * w;
            f2 += bf_lo(d.y) * w; f3 += bf_hi(d.y) * w;
            s += w;
        }
    }
    f0 += __shfl_xor(f0, 32); f1 += __shfl_xor(f1, 32);
    f2 += __shfl_xor(f2, 32); f3 += __shfl_xor(f3, 32);
    s  += __shfl_xor(s, 32);
    if (slot == 0) {
        const float inv = 1.f / (s + 1e-16f);
        const float4 bv = ((const float4*)bias)[cc];
        float4 o = make_float4(f0 * inv + bv.x, f1 * inv + bv.y,
                               f2 * inv + bv.z, f3 * inv + bv.w);
        ((float4*)out)[(unsigned)node * 32u + (unsigned)cc] = o;
    }
}

extern "C" void kernel_launch(void* const* d_in, const int* in_sizes, int n_in,
                              void* d_out, int out_size, void* d_ws, size_t ws_size,
                              hipStream_t stream) {
    const float* x       = (const float*)d_in[0];
    const int*   ei      = (const int*)d_in[1];
    const float* W       = (const float*)d_in[2];
    const float* att_src = (const float*)d_in[3];
    const float* att_dst = (const float*)d_in[4];
    const float* bias    = (const float*)d_in[5];
    float* out = (float*)d_out;

    const int N = in_sizes[0] / HC;
    const int E = in_sizes[1] / 2;
    const int B = (N + BKT_MSK) >> BKT_SH;     // buckets of 256 nodes (<= MAXB)
    const int nbin = (E + EPB - 1) / EPB;

    // ws: h16[N*64]u32 | a_src[N*8]f | a_dst[N*8]f | bcount[MAXB] |
    //     bptr[MAXB+1] | gcursor[MAXB] | rowptr[N+1] | col[E] | pairs[E]
    unsigned* h16 = (unsigned*)d_ws;
    float* a_src  = (float*)(h16 + (size_t)N * 64);
    float* a_dst  = a_src + (size_t)N * H;
    int* bcount   = (int*)(a_dst + (size_t)N * H);
    int* bptr     = bcount + MAXB;
    int* gcursor  = bptr + (MAXB + 1);
    int* rowptr   = gcursor + MAXB;
    int* col      = rowptr + (N + 1);
    unsigned* pairs = (unsigned*)(col + E);

    // Fork-join: CSR chain (depends only on ei) runs on a side stream,
    // concurrent with k1_gemm (depends only on x,W). Capture-legal pattern:
    // event-record on capturing stream + stream-wait brings the side stream
    // into the capture graph. Static creation happens host-side (allowed).
    static hipStream_t s_side = nullptr;
    static hipEvent_t ev_fork = nullptr, ev_join = nullptr;
    if (s_side == nullptr) {
        (void)hipStreamCreateWithFlags(&s_side, hipStreamNonBlocking);
        (void)hipEventCreateWithFlags(&ev_fork, hipEventDisableTiming);
        (void)hipEventCreateWithFlags(&ev_join, hipEventDisableTiming);
    }
    const bool fork = (s_side != nullptr && ev_fork != nullptr && ev_join != nullptr);
    hipStream_t sb = fork ? s_side : stream;

    if (fork) {
        (void)hipEventRecord(ev_fork, stream);
        (void)hipStreamWaitEvent(sb, ev_fork, 0);
    }

    (void)hipMemsetAsync(bcount, 0, MAXB * sizeof(int), sb);
    kh_bucket<<<nbin, 256, 0, sb>>>(ei, bcount, E, B);
    kscan_b<<<1, 1024, 0, sb>>>(bcount, bptr, gcursor, rowptr, N, B, E);
    kb_bin<<<nbin, 256, 0, sb>>>(ei, gcursor, pairs, E, B);
    kb_final<<<B, 256, 0, sb>>>(pairs, bptr, rowptr, col, N);
    if (fork) (void)hipEventRecord(ev_join, sb);

    k1_gemm<<<(N + 63) / 64, 256, 0, stream>>>(x, W, att_src, att_dst,
                                               h16, a_src, a_dst, N);

    if (fork) (void)hipStreamWaitEvent(stream, ev_join, 0);

    k_pull<<<(N + 3) / 4, 256, 0, stream>>>(rowptr, col, h16, a_src,
                                            a_dst, bias, out, N);
}